// Round 14
// baseline (550.110 us; speedup 1.0000x reference)
//
#include <hip/hip_runtime.h>
#include <cmath>

#define TBL_SIZE (1u << 19)
#define TBL_MASK (TBL_SIZE - 1u)
#define PRIME1 2654435761u
#define PRIME2 805459861u
#define NUM_LEVELS 16
#define PPB 32      // points per 256-thr block, hashed path (8 lanes/point)

// Dense LDS-resident levels 0..2 (resolutions 16,21,27 -> dims s+1)
#define D0g 17
#define D1g 22
#define D2g 28
#define NW0 (D0g*D0g*D0g)        // 4913
#define NW1 (D1g*D1g*D1g)        // 10648
#define NW2 (D2g*D2g*D2g)        // 21952
#define NWTOT (NW0+NW1+NW2)      // 37513 words in ws (unpadded)
// LDS layout with per-level pad = max static corner offset (D*D+D+1), zeroed.
#define PAD0 (D0g*D0g+D0g+1)     // 307
#define PAD1 (D1g*D1g+D1g+1)     // 507
#define PAD2 (D2g*D2g+D2g+1)     // 813
#define LB0  0
#define LB1  (LB0+NW0+PAD0)
#define LB2  (LB1+NW1+PAD1)
#define LTOT (LB2+NW2+PAD2)      // 39140 words = 156560 B <= 160KB
#define LDSB (LTOT*4)

struct Args { float s[NUM_LEVELS]; };

typedef float v2f __attribute__((ext_vector_type(2)));
typedef float v4f __attribute__((ext_vector_type(4)));
typedef unsigned int v2u __attribute__((ext_vector_type(2)));

template<int CTRL>
__device__ __forceinline__ float dpp_add(float v) {
    int i = __builtin_bit_cast(int, v);
    int j = __builtin_amdgcn_mov_dpp(i, CTRL, 0xF, 0xF, true);
    return v + __builtin_bit_cast(float, j);
}

__device__ __forceinline__ uint32_t f2bf(float f) {  // f32->bf16 RNE (no NaN in data)
    uint32_t u = __builtin_bit_cast(uint32_t, f);
    return (u + 0x7FFFu + ((u >> 16) & 1u)) >> 16;
}
__device__ __forceinline__ float bflo(uint32_t v) { return __builtin_bit_cast(float, v << 16); }
__device__ __forceinline__ float bfhi(uint32_t v) { return __builtin_bit_cast(float, v & 0xFFFF0000u); }

// One launch: dense tables for levels 0..2 (first NWTOT ids) + bf16-pack levels
// 3..15 (remaining ids, TWO entries per thread via float4) into ws.
__global__ __launch_bounds__(256) void prep_kernel(
    const float* __restrict__ table, uint32_t* __restrict__ bfws,
    uint32_t* __restrict__ densews, int ncvt2)
{
    int gid = blockIdx.x * 256 + (int)threadIdx.x;
    if (gid < NWTOT) {
        int l, rel, D;
        if (gid < NW0)            { l = 0; rel = gid;             D = D0g; }
        else if (gid < NW0 + NW1) { l = 1; rel = gid - NW0;       D = D1g; }
        else                      { l = 2; rel = gid - NW0 - NW1; D = D2g; }
        int d2 = D * D;
        int xp = rel / d2; int rem = rel - xp * d2;
        int yp = rem / D;  int zp = rem - yp * D;
        uint32_t h = (uint32_t)xp ^ ((uint32_t)yp * PRIME1) ^ ((uint32_t)zp * PRIME2);
        float2 e = reinterpret_cast<const float2*>(table)[((size_t)l << 19) + (h & TBL_MASK)];
        densews[gid] = f2bf(e.x) | (f2bf(e.y) << 16);
    } else {
        int rel = gid - NWTOT;               // pair-of-entries index
        if (rel >= ncvt2) return;
        const float4* src = reinterpret_cast<const float4*>(table + (((size_t)3 << 19) * 2));
        float4 e = src[rel];
        v2u o;
        o.x = f2bf(e.x) | (f2bf(e.y) << 16);
        o.y = f2bf(e.z) | (f2bf(e.w) << 16);
        *reinterpret_cast<v2u*>(bfws + (size_t)rel * 2) = o;
    }
}

// Levels 0..2 from LDS, POINT-per-thread: 24 ds_read_b32 with static offsets,
// no dpp, one float4+float2 store per point (levels 0..2 contiguous in out).
__global__ __launch_bounds__(1024) void lds_levels_kernel(
    const float* __restrict__ x, const uint32_t* __restrict__ densews,
    float* __restrict__ out, int npoints,
    float s0, float s1, float s2)
{
    extern __shared__ uint32_t lds[];
    for (int i = (int)threadIdx.x; i < LTOT; i += 1024) lds[i] = 0;
    __syncthreads();
    for (int i = (int)threadIdx.x; i < NW0; i += 1024) lds[LB0 + i] = densews[i];
    for (int i = (int)threadIdx.x; i < NW1; i += 1024) lds[LB1 + i] = densews[NW0 + i];
    for (int i = (int)threadIdx.x; i < NW2; i += 1024) lds[LB2 + i] = densews[NW0 + NW1 + i];
    __syncthreads();

    float acc[6];
    for (int n = blockIdx.x * 1024 + (int)threadIdx.x; n < npoints; n += (int)gridDim.x * 1024) {
        float x0 = x[(size_t)n * 3 + 0] * 0.5f + 0.5f;
        float x1 = x[(size_t)n * 3 + 1] * 0.5f + 0.5f;
        float x2 = x[(size_t)n * 3 + 2] * 0.5f + 0.5f;

#define DO_LEVEL(LI, DCONST, LBASE, SCALE)                                        \
        {                                                                         \
            const int D = DCONST, D2 = DCONST * DCONST;                           \
            float sx = x0 * SCALE, sy = x1 * SCALE, sz = x2 * SCALE;              \
            float fx = floorf(sx), fy = floorf(sy), fz = floorf(sz);              \
            float ox = sx - fx, oy = sy - fy, oz = sz - fz;                       \
            int base = LBASE + ((int)fx * D + (int)fy) * D + (int)fz;             \
            uint32_t v000 = lds[base];            uint32_t v001 = lds[base + 1];  \
            uint32_t v010 = lds[base + D];        uint32_t v011 = lds[base + D + 1]; \
            uint32_t v100 = lds[base + D2];       uint32_t v101 = lds[base + D2 + 1]; \
            uint32_t v110 = lds[base + D2 + D];   uint32_t v111 = lds[base + D2 + D + 1]; \
            float gx0 = 1.f - ox, gy0 = 1.f - oy, gz0 = 1.f - oz;                 \
            float w000 = gx0 * gy0 * gz0, w001 = gx0 * gy0 * oz;                  \
            float w010 = gx0 * oy * gz0,  w011 = gx0 * oy * oz;                   \
            float w100 = ox * gy0 * gz0,  w101 = ox * gy0 * oz;                   \
            float w110 = ox * oy * gz0,   w111 = ox * oy * oz;                    \
            acc[LI*2+0] = bflo(v000)*w000 + bflo(v001)*w001 + bflo(v010)*w010     \
                        + bflo(v011)*w011 + bflo(v100)*w100 + bflo(v101)*w101     \
                        + bflo(v110)*w110 + bflo(v111)*w111;                      \
            acc[LI*2+1] = bfhi(v000)*w000 + bfhi(v001)*w001 + bfhi(v010)*w010     \
                        + bfhi(v011)*w011 + bfhi(v100)*w100 + bfhi(v101)*w101     \
                        + bfhi(v110)*w110 + bfhi(v111)*w111;                      \
        }
        DO_LEVEL(0, D0g, LB0, s0)
        DO_LEVEL(1, D1g, LB1, s1)
        DO_LEVEL(2, D2g, LB2, s2)
#undef DO_LEVEL

        v4f a; a.x = acc[0]; a.y = acc[1]; a.z = acc[2]; a.w = acc[3];
        v2f b; b.x = acc[4]; b.y = acc[5];
        float* o = out + (size_t)n * 32;
        __builtin_nontemporal_store(a, (v4f*)o);
        __builtin_nontemporal_store(b, (v2f*)(o + 4));
    }
}

// Hashed levels [L0,16): corner-per-lane, bf16 (li<NBF) else f32. XCD-affine
// contiguous split. THE ONE CHANGE vs r12: gathers are NONTEMPORAL (L1 bypass)
// to test whether the 2.19 cy/request floor is L1-miss-path overhead.
__global__ __launch_bounds__(256) void HashEncoding_88837103551034_kernel(
    const float* __restrict__ x,
    const float* __restrict__ table,
    const uint32_t* __restrict__ bfws,
    float* __restrict__ out,
    int npoints, int CH, int perXcd, int total, int L0, int NBF,
    Args args)
{
    int b = blockIdx.x; int xcd = b & 7; int sb = b >> 3;
    int g = xcd * perXcd + sb;
    if (g >= total) return;
    int li = g / CH; int level = L0 + li; int chunk = g - li * CH;
    int t = (int)threadIdx.x;
    int corner = t & 7;
    int n = chunk * PPB + (t >> 3);
    if (n >= npoints) return;

    float x0 = x[(size_t)n * 3 + 0] * 0.5f + 0.5f;
    float x1 = x[(size_t)n * 3 + 1] * 0.5f + 0.5f;
    float x2 = x[(size_t)n * 3 + 2] * 0.5f + 0.5f;
    float sl = args.s[level];
    float sx = x0 * sl, sy = x1 * sl, sz = x2 * sl;
    float fx = floorf(sx), fy = floorf(sy), fz = floorf(sz);
    float ox = sx - fx, oy = sy - fy, oz = sz - fz;
    int bx = (corner >> 2) & 1, by = (corner >> 1) & 1, bz = corner & 1;

    // ceil==floor+1 except integral coords, where the ceil-corner weight is 0.
    uint32_t h = (uint32_t)((int)fx + bx)
               ^ ((uint32_t)((int)fy + by) * PRIME1)
               ^ ((uint32_t)((int)fz + bz) * PRIME2);
    uint32_t idx = h & TBL_MASK;

    float f0, f1;
    if (li < NBF) {
        uint32_t v = __builtin_nontemporal_load(&bfws[((size_t)li << 19) + idx]);
        f0 = bflo(v); f1 = bfhi(v);
    } else {
        const float2* fp = reinterpret_cast<const float2*>(table) + ((size_t)level << 19) + idx;
        v2u raw = __builtin_nontemporal_load(reinterpret_cast<const v2u*>(fp));
        f0 = __builtin_bit_cast(float, raw.x);
        f1 = __builtin_bit_cast(float, raw.y);
    }
    float w = (bx ? ox : 1.f - ox) * (by ? oy : 1.f - oy) * (bz ? oz : 1.f - oz);
    float e0 = f0 * w, e1 = f1 * w;
    e0 = dpp_add<0xB1>(e0);  e1 = dpp_add<0xB1>(e1);   // xor1
    e0 = dpp_add<0x4E>(e0);  e1 = dpp_add<0x4E>(e1);   // xor2
    e0 = dpp_add<0x141>(e0); e1 = dpp_add<0x141>(e1);  // half-row mirror (0<-7)
    if (corner == 0) {
        v2f res; res.x = e0; res.y = e1;
        __builtin_nontemporal_store(res, (v2f*)(out + (size_t)n * 32 + level * 2));
    }
}

extern "C" void kernel_launch(void* const* d_in, const int* in_sizes, int n_in,
                              void* d_out, int out_size, void* d_ws, size_t ws_size,
                              hipStream_t stream) {
    const float* x = (const float*)d_in[0];
    const float* table = (const float*)d_in[1];
    float* out = (float*)d_out;
    int npoints = in_sizes[0] / 3;

    Args args;
    double growth = std::exp((std::log(1024.0) - std::log(16.0)) / 15.0);
    for (int l = 0; l < NUM_LEVELS; ++l)
        args.s[l] = (float)std::floor(16.0 * std::pow(growth, (double)l));

    int CH = (npoints + PPB - 1) / PPB;
    uint32_t* ws32 = (uint32_t*)d_ws;

    bool dimsOk = ((int)args.s[0] == 16) && ((int)args.s[1] == 21) && ((int)args.s[2] == 27);
    size_t needA = ((size_t)13 * TBL_SIZE + (size_t)NWTOT) * 4;   // ~27.4MB

    if (dimsOk && ws_size >= needA) {
        // Plan A: LDS levels 0-2 (point-per-thread), bf16-hashed levels 3-15.
        uint32_t* wsdense = ws32 + (size_t)13 * TBL_SIZE;
        int ncvt2 = 13 << 18;                 // entry-pairs
        int ptot = NWTOT + ncvt2;
        prep_kernel<<<(ptot + 255) / 256, 256, 0, stream>>>(table, ws32, wsdense, ncvt2);

        hipFuncSetAttribute(reinterpret_cast<const void*>(lds_levels_kernel),
                            hipFuncAttributeMaxDynamicSharedMemorySize, LDSB);
        lds_levels_kernel<<<256, 1024, LDSB, stream>>>(
            x, wsdense, out, npoints, args.s[0], args.s[1], args.s[2]);

        int total = 13 * CH;
        int perXcd = (total + 7) / 8;
        HashEncoding_88837103551034_kernel<<<8 * perXcd, 256, 0, stream>>>(
            x, table, ws32, out, npoints, CH, perXcd, total, 3, 13, args);
    } else {
        // Plan C: all 16 levels hashed from f32 table (proven fallback).
        int total = 16 * CH;
        int perXcd = (total + 7) / 8;
        HashEncoding_88837103551034_kernel<<<8 * perXcd, 256, 0, stream>>>(
            x, table, ws32, out, npoints, CH, perXcd, total, 0, 0, args);
    }
}

// Round 15
// 248.881 us; speedup vs baseline: 2.2103x; 2.2103x over previous
//
#include <hip/hip_runtime.h>
#include <cmath>

#define TBL_SIZE (1u << 19)
#define TBL_MASK (TBL_SIZE - 1u)
#define PRIME1 2654435761u
#define PRIME2 805459861u
#define NUM_LEVELS 16
#define PPB 32      // points per 256-thr block, hashed path (8 lanes/point)

// Dense LDS-resident levels 0..2 (resolutions 16,21,27 -> dims s+1)
#define D0g 17
#define D1g 22
#define D2g 28
#define NW0 (D0g*D0g*D0g)        // 4913
#define NW1 (D1g*D1g*D1g)        // 10648
#define NW2 (D2g*D2g*D2g)        // 21952
#define NWTOT (NW0+NW1+NW2)      // 37513 words in ws (unpadded)
// LDS layout with per-level pad = max static corner offset (D*D+D+1), zeroed.
#define PAD0 (D0g*D0g+D0g+1)     // 307
#define PAD1 (D1g*D1g+D1g+1)     // 507
#define PAD2 (D2g*D2g+D2g+1)     // 813
#define LB0  0
#define LB1  (LB0+NW0+PAD0)
#define LB2  (LB1+NW1+PAD1)
#define LTOT (LB2+NW2+PAD2)      // 39140 words = 156560 B <= 160KB
#define LDSB (LTOT*4)

struct Args { float s[NUM_LEVELS]; };

typedef float v2f __attribute__((ext_vector_type(2)));
typedef float v4f __attribute__((ext_vector_type(4)));
typedef unsigned int v2u __attribute__((ext_vector_type(2)));

template<int CTRL>
__device__ __forceinline__ float dpp_add(float v) {
    int i = __builtin_bit_cast(int, v);
    int j = __builtin_amdgcn_mov_dpp(i, CTRL, 0xF, 0xF, true);
    return v + __builtin_bit_cast(float, j);
}

__device__ __forceinline__ uint32_t f2bf(float f) {  // f32->bf16 RNE (no NaN in data)
    uint32_t u = __builtin_bit_cast(uint32_t, f);
    return (u + 0x7FFFu + ((u >> 16) & 1u)) >> 16;
}
__device__ __forceinline__ float bflo(uint32_t v) { return __builtin_bit_cast(float, v << 16); }
__device__ __forceinline__ float bfhi(uint32_t v) { return __builtin_bit_cast(float, v & 0xFFFF0000u); }

// One launch: dense tables for levels 0..2 (first NWTOT ids) + bf16-pack levels
// 3..15 (remaining ids, TWO entries per thread via float4) into ws.
__global__ __launch_bounds__(256) void prep_kernel(
    const float* __restrict__ table, uint32_t* __restrict__ bfws,
    uint32_t* __restrict__ densews, int ncvt2)
{
    int gid = blockIdx.x * 256 + (int)threadIdx.x;
    if (gid < NWTOT) {
        int l, rel, D;
        if (gid < NW0)            { l = 0; rel = gid;             D = D0g; }
        else if (gid < NW0 + NW1) { l = 1; rel = gid - NW0;       D = D1g; }
        else                      { l = 2; rel = gid - NW0 - NW1; D = D2g; }
        int d2 = D * D;
        int xp = rel / d2; int rem = rel - xp * d2;
        int yp = rem / D;  int zp = rem - yp * D;
        uint32_t h = (uint32_t)xp ^ ((uint32_t)yp * PRIME1) ^ ((uint32_t)zp * PRIME2);
        float2 e = reinterpret_cast<const float2*>(table)[((size_t)l << 19) + (h & TBL_MASK)];
        densews[gid] = f2bf(e.x) | (f2bf(e.y) << 16);
    } else {
        int rel = gid - NWTOT;               // pair-of-entries index
        if (rel >= ncvt2) return;
        const float4* src = reinterpret_cast<const float4*>(table + (((size_t)3 << 19) * 2));
        float4 e = src[rel];
        v2u o;
        o.x = f2bf(e.x) | (f2bf(e.y) << 16);
        o.y = f2bf(e.z) | (f2bf(e.w) << 16);
        *reinterpret_cast<v2u*>(bfws + (size_t)rel * 2) = o;
    }
}

// Levels 0..2 from LDS, POINT-per-thread: 24 ds_read_b32 with static offsets,
// no dpp, one float4+float2 store per point (levels 0..2 contiguous in out).
__global__ __launch_bounds__(1024) void lds_levels_kernel(
    const float* __restrict__ x, const uint32_t* __restrict__ densews,
    float* __restrict__ out, int npoints,
    float s0, float s1, float s2)
{
    extern __shared__ uint32_t lds[];
    for (int i = (int)threadIdx.x; i < LTOT; i += 1024) lds[i] = 0;
    __syncthreads();
    for (int i = (int)threadIdx.x; i < NW0; i += 1024) lds[LB0 + i] = densews[i];
    for (int i = (int)threadIdx.x; i < NW1; i += 1024) lds[LB1 + i] = densews[NW0 + i];
    for (int i = (int)threadIdx.x; i < NW2; i += 1024) lds[LB2 + i] = densews[NW0 + NW1 + i];
    __syncthreads();

    float acc[6];
    for (int n = blockIdx.x * 1024 + (int)threadIdx.x; n < npoints; n += (int)gridDim.x * 1024) {
        float x0 = x[(size_t)n * 3 + 0] * 0.5f + 0.5f;
        float x1 = x[(size_t)n * 3 + 1] * 0.5f + 0.5f;
        float x2 = x[(size_t)n * 3 + 2] * 0.5f + 0.5f;

#define DO_LEVEL(LI, DCONST, LBASE, SCALE)                                        \
        {                                                                         \
            const int D = DCONST, D2 = DCONST * DCONST;                           \
            float sx = x0 * SCALE, sy = x1 * SCALE, sz = x2 * SCALE;              \
            float fx = floorf(sx), fy = floorf(sy), fz = floorf(sz);              \
            float ox = sx - fx, oy = sy - fy, oz = sz - fz;                       \
            int base = LBASE + ((int)fx * D + (int)fy) * D + (int)fz;             \
            uint32_t v000 = lds[base];            uint32_t v001 = lds[base + 1];  \
            uint32_t v010 = lds[base + D];        uint32_t v011 = lds[base + D + 1]; \
            uint32_t v100 = lds[base + D2];       uint32_t v101 = lds[base + D2 + 1]; \
            uint32_t v110 = lds[base + D2 + D];   uint32_t v111 = lds[base + D2 + D + 1]; \
            float gx0 = 1.f - ox, gy0 = 1.f - oy, gz0 = 1.f - oz;                 \
            float w000 = gx0 * gy0 * gz0, w001 = gx0 * gy0 * oz;                  \
            float w010 = gx0 * oy * gz0,  w011 = gx0 * oy * oz;                   \
            float w100 = ox * gy0 * gz0,  w101 = ox * gy0 * oz;                   \
            float w110 = ox * oy * gz0,   w111 = ox * oy * oz;                    \
            acc[LI*2+0] = bflo(v000)*w000 + bflo(v001)*w001 + bflo(v010)*w010     \
                        + bflo(v011)*w011 + bflo(v100)*w100 + bflo(v101)*w101     \
                        + bflo(v110)*w110 + bflo(v111)*w111;                      \
            acc[LI*2+1] = bfhi(v000)*w000 + bfhi(v001)*w001 + bfhi(v010)*w010     \
                        + bfhi(v011)*w011 + bfhi(v100)*w100 + bfhi(v101)*w101     \
                        + bfhi(v110)*w110 + bfhi(v111)*w111;                      \
        }
        DO_LEVEL(0, D0g, LB0, s0)
        DO_LEVEL(1, D1g, LB1, s1)
        DO_LEVEL(2, D2g, LB2, s2)
#undef DO_LEVEL

        v4f a; a.x = acc[0]; a.y = acc[1]; a.z = acc[2]; a.w = acc[3];
        v2f b; b.x = acc[4]; b.y = acc[5];
        float* o = out + (size_t)n * 32;
        __builtin_nontemporal_store(a, (v4f*)o);
        __builtin_nontemporal_store(b, (v2f*)(o + 4));
    }
}

// Hashed levels [L0,16): corner-per-lane, bf16 (li<NBF) else f32. XCD-affine
// contiguous split. Normal cached gathers (proven at the TCP request floor).
__global__ __launch_bounds__(256) void HashEncoding_88837103551034_kernel(
    const float* __restrict__ x,
    const float* __restrict__ table,
    const uint32_t* __restrict__ bfws,
    float* __restrict__ out,
    int npoints, int CH, int perXcd, int total, int L0, int NBF,
    Args args)
{
    int b = blockIdx.x; int xcd = b & 7; int sb = b >> 3;
    int g = xcd * perXcd + sb;
    if (g >= total) return;
    int li = g / CH; int level = L0 + li; int chunk = g - li * CH;
    int t = (int)threadIdx.x;
    int corner = t & 7;
    int n = chunk * PPB + (t >> 3);
    if (n >= npoints) return;

    float x0 = x[(size_t)n * 3 + 0] * 0.5f + 0.5f;
    float x1 = x[(size_t)n * 3 + 1] * 0.5f + 0.5f;
    float x2 = x[(size_t)n * 3 + 2] * 0.5f + 0.5f;
    float sl = args.s[level];
    float sx = x0 * sl, sy = x1 * sl, sz = x2 * sl;
    float fx = floorf(sx), fy = floorf(sy), fz = floorf(sz);
    float ox = sx - fx, oy = sy - fy, oz = sz - fz;
    int bx = (corner >> 2) & 1, by = (corner >> 1) & 1, bz = corner & 1;

    // ceil==floor+1 except integral coords, where the ceil-corner weight is 0.
    uint32_t h = (uint32_t)((int)fx + bx)
               ^ ((uint32_t)((int)fy + by) * PRIME1)
               ^ ((uint32_t)((int)fz + bz) * PRIME2);
    uint32_t idx = h & TBL_MASK;

    float f0, f1;
    if (li < NBF) {
        uint32_t v = bfws[((size_t)li << 19) + idx];
        f0 = bflo(v); f1 = bfhi(v);
    } else {
        float2 f = reinterpret_cast<const float2*>(table)[((size_t)level << 19) + idx];
        f0 = f.x; f1 = f.y;
    }
    float w = (bx ? ox : 1.f - ox) * (by ? oy : 1.f - oy) * (bz ? oz : 1.f - oz);
    float e0 = f0 * w, e1 = f1 * w;
    e0 = dpp_add<0xB1>(e0);  e1 = dpp_add<0xB1>(e1);   // xor1
    e0 = dpp_add<0x4E>(e0);  e1 = dpp_add<0x4E>(e1);   // xor2
    e0 = dpp_add<0x141>(e0); e1 = dpp_add<0x141>(e1);  // half-row mirror (0<-7)
    if (corner == 0) {
        v2f res; res.x = e0; res.y = e1;
        __builtin_nontemporal_store(res, (v2f*)(out + (size_t)n * 32 + level * 2));
    }
}

extern "C" void kernel_launch(void* const* d_in, const int* in_sizes, int n_in,
                              void* d_out, int out_size, void* d_ws, size_t ws_size,
                              hipStream_t stream) {
    const float* x = (const float*)d_in[0];
    const float* table = (const float*)d_in[1];
    float* out = (float*)d_out;
    int npoints = in_sizes[0] / 3;

    Args args;
    double growth = std::exp((std::log(1024.0) - std::log(16.0)) / 15.0);
    for (int l = 0; l < NUM_LEVELS; ++l)
        args.s[l] = (float)std::floor(16.0 * std::pow(growth, (double)l));

    int CH = (npoints + PPB - 1) / PPB;
    uint32_t* ws32 = (uint32_t*)d_ws;

    bool dimsOk = ((int)args.s[0] == 16) && ((int)args.s[1] == 21) && ((int)args.s[2] == 27);
    size_t needA = ((size_t)13 * TBL_SIZE + (size_t)NWTOT) * 4;   // ~27.4MB

    if (dimsOk && ws_size >= needA) {
        // Plan A: LDS levels 0-2 (point-per-thread), bf16-hashed levels 3-15.
        uint32_t* wsdense = ws32 + (size_t)13 * TBL_SIZE;
        int ncvt2 = 13 << 18;                 // entry-pairs
        int ptot = NWTOT + ncvt2;
        prep_kernel<<<(ptot + 255) / 256, 256, 0, stream>>>(table, ws32, wsdense, ncvt2);

        hipFuncSetAttribute(reinterpret_cast<const void*>(lds_levels_kernel),
                            hipFuncAttributeMaxDynamicSharedMemorySize, LDSB);
        lds_levels_kernel<<<256, 1024, LDSB, stream>>>(
            x, wsdense, out, npoints, args.s[0], args.s[1], args.s[2]);

        int total = 13 * CH;
        int perXcd = (total + 7) / 8;
        HashEncoding_88837103551034_kernel<<<8 * perXcd, 256, 0, stream>>>(
            x, table, ws32, out, npoints, CH, perXcd, total, 3, 13, args);
    } else {
        // Plan C: all 16 levels hashed from f32 table (proven fallback).
        int total = 16 * CH;
        int perXcd = (total + 7) / 8;
        HashEncoding_88837103551034_kernel<<<8 * perXcd, 256, 0, stream>>>(
            x, table, ws32, out, npoints, CH, perXcd, total, 0, 0, args);
    }
}